// Round 16
// baseline (27.002 us; speedup 1.0000x reference)
//
#include <hip/hip_runtime.h>
#include <math.h>

// Geometry (fixed): x (2,128,32,32) f32; gumbel (2,128,32,32,256) f32
// out: quantized (262144 f32) ++ rate (1 f32)
#define PIXELS    262144
#define NLEV      256
#define WIN       64            // 2 x 128B lines per pixel, exactly
#define LPP       8             // lanes per pixel
#define TILE_PIX  32            // pixels per 256-thread block
#define NBLOCKS   (PIXELS / TILE_PIX)   // 8192
#define NPART     (NBLOCKS * 4)         // one partial per wave

typedef float v4f __attribute__((ext_vector_type(4)));

// FROZEN memory shape (R4-R15 ablation): 8192 one-tile blocks, LPP=8,
// TWO independent dwordx4/lane (2KB/wave in flight). Deeper chains (R15),
// more loads (R7), fewer blocks (R4) all regress. Window b=(i0-16)&~31:
// margins [16,47], exactly 2 aligned 128B lines (256B/pixel) — byte floor;
// absmax stays at fp-noise 0.031 (thr 0.985). Fusion closed (R8/R11/R12/R13).
// R16: barrier-free blocks (per-wave rate partials via shfl, no LDS/syncs)
// + sl chunk factorization (fma(lev0, se_c, e1+2e2+3e3)).
__global__ __launch_bounds__(256) void quant_rate_kernel(
    const float* __restrict__ x,
    const float* __restrict__ scales,
    const float* __restrict__ medians,
    const float* __restrict__ ent_scales,
    const float* __restrict__ gumbel,
    float* __restrict__ out,
    float* __restrict__ partials)
{
    const int t    = threadIdx.x;
    const int sub  = t & (LPP - 1);               // lane within pixel group
    const int pb   = t >> 3;                      // pixel slot, 0..31
    const int lane = t & 63, wid = t >> 6;
    const int p    = blockIdx.x * TILE_PIX + pb;

    const int   c  = (p >> 10) & 127;             // uniform across the block
    const float s  = scales[c];
    const float xv = x[p];
    const float xs = xv * __builtin_amdgcn_rcpf(s);

    int b = (((int)rintf(xs) + 112) & ~31);       // (i0-16)&~31, i0 = rint+128
    b = b < 0 ? 0 : (b > NLEV - WIN ? NLEV - WIN : b);

    const float* gp = gumbel + (size_t)p * NLEV + b + sub * 4;
    const v4f g0 = *reinterpret_cast<const v4f*>(gp);        // line 0
    const v4f g1 = *reinterpret_cast<const v4f*>(gp + 32);   // line 1

    float se, sl;
    {
        const float lev0 = (float)(b + sub * 4 - 128);
        const float e0 = __expf(g0.x - fabsf(xs - lev0));
        const float e1 = __expf(g0.y - fabsf(xs - (lev0 + 1.f)));
        const float e2 = __expf(g0.z - fabsf(xs - (lev0 + 2.f)));
        const float e3 = __expf(g0.w - fabsf(xs - (lev0 + 3.f)));
        const float sec = (e0 + e1) + (e2 + e3);
        const float tc  = fmaf(2.f, e2, e1) + 3.f * e3;
        se = sec;
        sl = fmaf(lev0, sec, tc);
    }
    {
        const float lev0 = (float)(b + sub * 4 + 32 - 128);
        const float e0 = __expf(g1.x - fabsf(xs - lev0));
        const float e1 = __expf(g1.y - fabsf(xs - (lev0 + 1.f)));
        const float e2 = __expf(g1.z - fabsf(xs - (lev0 + 2.f)));
        const float e3 = __expf(g1.w - fabsf(xs - (lev0 + 3.f)));
        const float sec = (e0 + e1) + (e2 + e3);
        const float tc  = fmaf(2.f, e2, e1) + 3.f * e3;
        se += sec;
        sl += fmaf(lev0, sec, tc);
    }

    #pragma unroll
    for (int o = 4; o; o >>= 1) {
        se += __shfl_xor(se, o);
        sl += __shfl_xor(sl, o);
    }
    if (sub == 0) out[p] = sl * __builtin_amdgcn_rcpf(se) * s;

    // ---- rate partial: per-wave, barrier-free ----
    float m_ = 0.f, inv_ = 0.f, k1_ = 0.f;
    if (lane == 0) {                              // once per wave
        const float es = ent_scales[c];
        const float sp = (es > 20.f) ? es : __logf(1.f + __expf(es));
        m_   = medians[c];
        inv_ = __builtin_amdgcn_rcpf(sp);
        k1_  = -0.5f * __logf(2.f * (float)M_PI * sp * sp);
    }
    m_ = __shfl(m_, 0); inv_ = __shfl(inv_, 0); k1_ = __shfl(k1_, 0);

    float ll = 0.f;
    if (sub == 0) {
        const float d = (xv - m_) * inv_;
        ll = fmaf(d * d, -0.5f, k1_);
    }
    #pragma unroll
    for (int o = 32; o; o >>= 1) ll += __shfl_xor(ll, o);
    if (lane == 0) partials[blockIdx.x * 4 + wid] = ll;
}

__global__ __launch_bounds__(1024) void rate_final(
    const float* __restrict__ partials, float* __restrict__ out)
{
    float acc = 0.f;
    #pragma unroll
    for (int i = threadIdx.x; i < NPART; i += 1024) acc += partials[i];
    #pragma unroll
    for (int o = 32; o; o >>= 1) acc += __shfl_xor(acc, o);
    __shared__ float sd[16];
    if ((threadIdx.x & 63) == 0) sd[threadIdx.x >> 6] = acc;
    __syncthreads();
    if (threadIdx.x == 0) {
        float tot = 0.f;
        #pragma unroll
        for (int i = 0; i < 16; ++i) tot += sd[i];
        out[PIXELS] = -tot / (float)PIXELS;
    }
}

extern "C" void kernel_launch(void* const* d_in, const int* in_sizes, int n_in,
                              void* d_out, int out_size, void* d_ws, size_t ws_size,
                              hipStream_t stream)
{
    const float* x          = (const float*)d_in[0];
    const float* scales     = (const float*)d_in[1];
    const float* medians    = (const float*)d_in[2];
    const float* ent_scales = (const float*)d_in[3];
    const float* gumbel     = (const float*)d_in[4];
    float* out      = (float*)d_out;
    float* partials = (float*)d_ws;     // 32768 floats = 128 KiB scratch

    quant_rate_kernel<<<NBLOCKS, 256, 0, stream>>>(
        x, scales, medians, ent_scales, gumbel, out, partials);
    rate_final<<<1, 1024, 0, stream>>>(partials, out);
}

// Round 17
// 18.897 us; speedup vs baseline: 1.4289x; 1.4289x over previous
//
#include <hip/hip_runtime.h>
#include <math.h>

// Geometry (fixed): x (2,128,32,32) f32; gumbel (2,128,32,32,256) f32
// out: quantized (262144 f32) ++ rate (1 f32)
#define PIXELS    262144
#define NLEV      256
#define WIN       64            // 2 x 128B lines per pixel, exactly
#define LPP       8             // lanes per pixel, 2 independent float4 each
#define TILE_PIX  32            // pixels per 256-thread block (ONE c per block)
#define NBLOCKS   (PIXELS / TILE_PIX)   // 8192

typedef float v4f __attribute__((ext_vector_type(4)));

// FINAL (R14 structure — measured optimum of the session):
// Window: b = (i0-16) & ~31 (i0 = nearest level). Margins in [16,47] both
// sides; window = exactly TWO aligned 128B cache lines (256B/pixel, zero
// partial-line waste). Margin 16 is the safety floor; absmax stays at
// fp-noise 0.031 (threshold 0.985).
// Memory shape (R4-R15 ablation): 8192 one-tile blocks, LPP=8, TWO
// independent dwordx4/lane (2KB/wave in flight). Deeper per-thread chains
// (R15), more loads/lane (R7), fewer blocks (R4/R5) all regress.
// Rate path: block-level LDS reduce (2 cheap barriers); per-wave shuffle
// variant regresses 8us (R16 — DS-pipe overhead). In-kernel fusion closed
// (R8 release fence 10x, R11 relaxed atomics 5x, R12/R13 dedicated block).
__global__ __launch_bounds__(256) void quant_rate_kernel(
    const float* __restrict__ x,
    const float* __restrict__ scales,
    const float* __restrict__ medians,
    const float* __restrict__ ent_scales,
    const float* __restrict__ gumbel,
    float* __restrict__ out,
    float* __restrict__ partials)
{
    const int t   = threadIdx.x;
    const int sub = t & (LPP - 1);                // lane within pixel group
    const int pb  = t >> 3;                       // pixel slot, 0..31
    const int p   = blockIdx.x * TILE_PIX + pb;

    const int   c  = (p >> 10) & 127;             // uniform across the block
    const float s  = scales[c];
    const float xv = x[p];
    const float xs = xv * __builtin_amdgcn_rcpf(s);

    int b = (((int)rintf(xs) + 112) & ~31);       // (i0-16)&~31, i0 = rint+128
    b = b < 0 ? 0 : (b > NLEV - WIN ? NLEV - WIN : b);

    const float* gp = gumbel + (size_t)p * NLEV + b + sub * 4;
    const v4f g0 = *reinterpret_cast<const v4f*>(gp);        // line 0
    const v4f g1 = *reinterpret_cast<const v4f*>(gp + 32);   // line 1

    __shared__ float sdata[TILE_PIX];
    __shared__ float rc[3];                       // {median, 1/sp, k1}
    if (t == 0) {
        const float es = ent_scales[c];
        const float sp = (es > 20.f) ? es : __logf(1.f + __expf(es));
        rc[0] = medians[c];
        rc[1] = __builtin_amdgcn_rcpf(sp);
        rc[2] = -0.5f * __logf(2.f * (float)M_PI * sp * sp);
    }

    float se, sl;
    {
        const float lev0 = (float)(b + sub * 4 - 128);
        const float e0 = __expf(g0.x - fabsf(xs - lev0));
        const float e1 = __expf(g0.y - fabsf(xs - (lev0 + 1.f)));
        const float e2 = __expf(g0.z - fabsf(xs - (lev0 + 2.f)));
        const float e3 = __expf(g0.w - fabsf(xs - (lev0 + 3.f)));
        se = (e0 + e1) + (e2 + e3);
        sl = (e0 * lev0 + e1 * (lev0 + 1.f)) + (e2 * (lev0 + 2.f) + e3 * (lev0 + 3.f));
    }
    {
        const float lev0 = (float)(b + sub * 4 + 32 - 128);
        const float e0 = __expf(g1.x - fabsf(xs - lev0));
        const float e1 = __expf(g1.y - fabsf(xs - (lev0 + 1.f)));
        const float e2 = __expf(g1.z - fabsf(xs - (lev0 + 2.f)));
        const float e3 = __expf(g1.w - fabsf(xs - (lev0 + 3.f)));
        se += (e0 + e1) + (e2 + e3);
        sl += (e0 * lev0 + e1 * (lev0 + 1.f)) + (e2 * (lev0 + 2.f) + e3 * (lev0 + 3.f));
    }

    #pragma unroll
    for (int o = 4; o; o >>= 1) {
        se += __shfl_xor(se, o);
        sl += __shfl_xor(sl, o);
    }
    if (sub == 0) out[p] = sl * __builtin_amdgcn_rcpf(se) * s;

    __syncthreads();                              // rc[] ready
    if (sub == 0) {
        const float d = (xv - rc[0]) * rc[1];
        sdata[pb] = fmaf(d * d, -0.5f, rc[2]);
    }
    __syncthreads();
    if (t == 0) {
        float acc = 0.f;
        #pragma unroll
        for (int i = 0; i < TILE_PIX; ++i) acc += sdata[i];
        partials[blockIdx.x] = acc;
    }
}

__global__ __launch_bounds__(1024) void rate_final(
    const float* __restrict__ partials, float* __restrict__ out)
{
    float acc = 0.f;
    #pragma unroll
    for (int i = threadIdx.x; i < NBLOCKS; i += 1024) acc += partials[i];
    #pragma unroll
    for (int o = 32; o; o >>= 1) acc += __shfl_xor(acc, o);
    __shared__ float sd[16];
    if ((threadIdx.x & 63) == 0) sd[threadIdx.x >> 6] = acc;
    __syncthreads();
    if (threadIdx.x == 0) {
        float tot = 0.f;
        #pragma unroll
        for (int i = 0; i < 16; ++i) tot += sd[i];
        out[PIXELS] = -tot / (float)PIXELS;
    }
}

extern "C" void kernel_launch(void* const* d_in, const int* in_sizes, int n_in,
                              void* d_out, int out_size, void* d_ws, size_t ws_size,
                              hipStream_t stream)
{
    const float* x          = (const float*)d_in[0];
    const float* scales     = (const float*)d_in[1];
    const float* medians    = (const float*)d_in[2];
    const float* ent_scales = (const float*)d_in[3];
    const float* gumbel     = (const float*)d_in[4];
    float* out      = (float*)d_out;
    float* partials = (float*)d_ws;     // 8192 floats = 32 KiB scratch

    quant_rate_kernel<<<NBLOCKS, 256, 0, stream>>>(
        x, scales, medians, ent_scales, gumbel, out, partials);
    rate_final<<<1, 1024, 0, stream>>>(partials, out);
}